// Round 1
// baseline (203.005 us; speedup 1.0000x reference)
//
#include <hip/hip_runtime.h>
#include <hip/hip_bf16.h>

#define N_NODES 50000
#define N_EDGES 800000
#define IN_F 128      // tail features of x (x has 129 components)
#define OUT_C 128     // output components per node

__device__ __forceinline__ float wave_reduce_sum(float v) {
    v += __shfl_xor(v, 32, 64);
    v += __shfl_xor(v, 16, 64);
    v += __shfl_xor(v, 8, 64);
    v += __shfl_xor(v, 4, 64);
    v += __shfl_xor(v, 2, 64);
    v += __shfl_xor(v, 1, 64);
    return v;   // all lanes hold the sum
}

__device__ __forceinline__ float arcosh_f(float z) {
    z = fmaxf(z, 1.0f + 1e-7f);
    return logf(z + sqrtf(z * z - 1.0f));
}

// ---------------------------------------------------------------------------
// Stage 1: h[node] = exp_map_zero( [0, W @ log_map_zero(x[node]).tail + b] )
// One wave (64 lanes) per node; lane holds features 2l, 2l+1.
// Weight transposed+padded in LDS, shared by the block's 8 waves.
// ---------------------------------------------------------------------------
__global__ __launch_bounds__(512) void transform_kernel(
        const float* __restrict__ x, const float* __restrict__ weight,
        const float* __restrict__ bias, float* __restrict__ h) {
    __shared__ float Wt[128 * 130];     // Wt[k*130 + j] = weight[j*128 + k]
    __shared__ float xt[8][128];

    const int tid = threadIdx.x;
    for (int idx = tid; idx < 127 * 128; idx += 512) {
        int j = idx >> 7, k = idx & 127;
        Wt[k * 130 + j] = weight[idx];
    }
    if (tid < 128) Wt[tid * 130 + 127] = 0.0f;   // pad column j=127

    const int wave = tid >> 6, lane = tid & 63;
    const int node = blockIdx.x * 8 + wave;      // grid exact: 6250*8 = 50000

    // log_map_zero
    const float* xp = x + (long)node * 129;
    float t0 = xp[1 + 2 * lane];
    float t1 = xp[2 + 2 * lane];
    float x0 = xp[0];
    float ssq = wave_reduce_sum(t0 * t0 + t1 * t1);
    float dist = arcosh_f(x0);
    float tnorm = sqrtf(fmaxf(ssq, 1e-6f));
    float sc = dist / tnorm;
    xt[wave][2 * lane]     = sc * t0;
    xt[wave][2 * lane + 1] = sc * t1;
    __syncthreads();

    // GEMV: mx[j] = sum_k xt[k] * W[j][k] + bias[j], j = 0..126
    const int j0 = 2 * lane, j1 = 2 * lane + 1;
    float acc0 = bias[j0];                       // j0 <= 126 always
    float acc1 = (j1 < 127) ? bias[j1] : 0.0f;
    const float* xw = xt[wave];
    #pragma unroll 8
    for (int k = 0; k < 128; ++k) {
        float xk = xw[k];
        float2 w = *(const float2*)&Wt[k * 130 + j0];
        acc0 = fmaf(xk, w.x, acc0);
        acc1 = fmaf(xk, w.y, acc1);
    }

    // exp_map_zero on v = [0, mx]
    float loc = acc0 * acc0 + ((j1 < 127) ? acc1 * acc1 : 0.0f);
    float S = wave_reduce_sum(loc);
    float n = sqrtf(fmaxf(S, 1e-6f));
    float r = sinhf(fminf(n, 50.0f)) / n;
    float head = sqrtf(1.0f + r * r * S);

    float* hp = h + (long)node * OUT_C;
    if (lane == 0) hp[0] = head;
    hp[1 + j0] = r * acc0;                       // comps 1,3,5,...,127
    if (j1 < 127) hp[1 + j1] = r * acc1;         // comps 2,4,...,126
}

// ---------------------------------------------------------------------------
// row_ptr[r] = first edge index with row >= r (rows are sorted)
// ---------------------------------------------------------------------------
__global__ void rowptr_kernel(const int* __restrict__ row, int* __restrict__ rowptr) {
    int e = blockIdx.x * 256 + threadIdx.x;
    if (e >= N_EDGES) return;
    int r1 = row[e];
    int r0 = (e == 0) ? -1 : row[e - 1];
    for (int r = r0 + 1; r <= r1; ++r) rowptr[r] = e;
    if (e == N_EDGES - 1) {
        for (int r = r1 + 1; r <= N_NODES; ++r) rowptr[r] = N_EDGES;
    }
}

// ---------------------------------------------------------------------------
// Stage 2+3: s = segment_sum(val * h[col]); lorentz centroid normalize; hyp_act
// One wave per node; lane holds components 2l, 2l+1 (comp 0 = head).
// ---------------------------------------------------------------------------
__global__ __launch_bounds__(256) void centroid_act_kernel(
        const float* __restrict__ h, const float* __restrict__ val,
        const int* __restrict__ col, const int* __restrict__ rowptr,
        float* __restrict__ out) {
    const int wave = threadIdx.x >> 6, lane = threadIdx.x & 63;
    const int node = blockIdx.x * 4 + wave;      // grid exact: 12500*4 = 50000

    const int lo = rowptr[node], hi = rowptr[node + 1];
    float s0 = 0.0f, s1 = 0.0f;
    for (int e = lo; e < hi; ++e) {
        int c = col[e];
        float v = val[e];
        float2 hv = *(const float2*)&h[(long)c * OUT_C + 2 * lane];
        s0 = fmaf(v, hv.x, s0);
        s1 = fmaf(v, hv.y, s1);
    }

    // inner = sum_{f>=1} s_f^2 - s_0^2
    float loc = s1 * s1 + ((lane == 0) ? -s0 * s0 : s0 * s0);
    float inner = wave_reduce_sum(loc);
    float coef = 1.0f / sqrtf(fmaxf(fabsf(inner), 1e-6f));

    float g0 = coef * s0, g1 = coef * s1;        // h2 components
    float h20 = coef * __shfl(s0, 0, 64);        // head component (lane0's)

    // hyp_act: relu(log_map_zero(h2)) then exp_map_zero
    float dist = arcosh_f(h20);
    float tloc = g1 * g1 + ((lane == 0) ? 0.0f : g0 * g0);
    float tsq = wave_reduce_sum(tloc);
    float tnorm = sqrtf(fmaxf(tsq, 1e-6f));
    float scl = dist / tnorm;

    float u0 = (lane == 0) ? 0.0f : fmaxf(scl * g0, 0.0f);
    float u1 = fmaxf(scl * g1, 0.0f);

    float S = wave_reduce_sum(u0 * u0 + u1 * u1);
    float n = sqrtf(fmaxf(S, 1e-6f));
    float r = sinhf(fminf(n, 50.0f)) / n;

    float o0 = (lane == 0) ? sqrtf(1.0f + r * r * S) : r * u0;
    float o1 = r * u1;
    *(float2*)&out[(long)node * OUT_C + 2 * lane] = make_float2(o0, o1);
}

extern "C" void kernel_launch(void* const* d_in, const int* in_sizes, int n_in,
                              void* d_out, int out_size, void* d_ws, size_t ws_size,
                              hipStream_t stream) {
    const float* x      = (const float*)d_in[0];
    const float* weight = (const float*)d_in[1];
    const float* bias   = (const float*)d_in[2];
    const float* adj_val = (const float*)d_in[3];
    const int*   adj_row = (const int*)d_in[4];
    const int*   adj_col = (const int*)d_in[5];
    float* out = (float*)d_out;

    float* h = (float*)d_ws;                                   // 50000*128*4 = 25.6 MB
    int* rowptr = (int*)((char*)d_ws + (size_t)N_NODES * OUT_C * 4);  // 50001 ints

    transform_kernel<<<N_NODES / 8, 512, 0, stream>>>(x, weight, bias, h);
    rowptr_kernel<<<(N_EDGES + 255) / 256, 256, 0, stream>>>(adj_row, rowptr);
    centroid_act_kernel<<<N_NODES / 4, 256, 0, stream>>>(h, adj_val, adj_col, rowptr, out);
}

// Round 2
// 144.125 us; speedup vs baseline: 1.4085x; 1.4085x over previous
//
#include <hip/hip_runtime.h>
#include <hip/hip_bf16.h>

#define NN 50000
#define NE 800000
#define XT_STRIDE 68   // 64 + 4: keeps float4 alignment, 8-way only on staging writes

__device__ __forceinline__ float wred64(float v) {
    v += __shfl_xor(v, 32, 64);
    v += __shfl_xor(v, 16, 64);
    v += __shfl_xor(v, 8, 64);
    v += __shfl_xor(v, 4, 64);
    v += __shfl_xor(v, 2, 64);
    v += __shfl_xor(v, 1, 64);
    return v;
}

__device__ __forceinline__ float arcosh_f(float z) {
    z = fmaxf(z, 1.0f + 1e-7f);
    return logf(z + sqrtf(z * z - 1.0f));
}

// ---------------------------------------------------------------------------
// One-time prep: WtT[k][j] = weight[j][k] (j=127 column zeroed), biasP padded.
// ---------------------------------------------------------------------------
__global__ void prep_kernel(const float* __restrict__ weight, const float* __restrict__ bias,
                            float* __restrict__ WtT, float* __restrict__ biasP) {
    int t = blockIdx.x * 256 + threadIdx.x;      // grid 64 -> 16384
    int k = t & 127, j = t >> 7;
    WtT[k * 128 + j] = (j < 127) ? weight[j * 128 + k] : 0.0f;
    if (t < 128) biasP[t] = (t < 127) ? bias[t] : 0.0f;
}

// ---------------------------------------------------------------------------
// rowptr[r] = first edge with row >= r (rows sorted)
// ---------------------------------------------------------------------------
__global__ void rowptr_kernel(const int* __restrict__ row, int* __restrict__ rowptr) {
    int e = blockIdx.x * 256 + threadIdx.x;
    if (e >= NE) return;
    int r1 = row[e];
    int r0 = (e == 0) ? -1 : row[e - 1];
    for (int r = r0 + 1; r <= r1; ++r) rowptr[r] = e;
    if (e == NE - 1) {
        for (int r = r1 + 1; r <= NN; ++r) rowptr[r] = NE;
    }
}

// ---------------------------------------------------------------------------
// Stage 1 as tiled GEMM: hh[node] = exp_map_zero([0, W @ log_map_zero(x).tail + b])
// Internal layout: hh[node][c] = tail_c for c<127, hh[node][127] = head.
// Block: 256 threads, 64 nodes. Thread (jg=t&31, ng=t>>5): 8 nodes x 4 outputs.
// LDS: Wt 64KB + xt 34.8KB (dynamic, 100352 B -> 1 block/CU).
// ---------------------------------------------------------------------------
__global__ __launch_bounds__(256) void transform_kernel(
        const float* __restrict__ x, const float* __restrict__ WtT,
        const float* __restrict__ biasP, float* __restrict__ hh) {
    extern __shared__ float smem[];
    float* Wt = smem;                 // [128][128]
    float* xt = smem + 128 * 128;     // [128][XT_STRIDE]

    const int tid = threadIdx.x;
    const int lane = tid & 63;
    const int w = tid >> 6;
    const int base = blockIdx.x * 64;

    // stage W (flat coalesced copy, conflict-free)
    #pragma unroll
    for (int i = 0; i < 16; ++i) {
        int idx = i * 256 + tid;
        ((float4*)Wt)[idx] = ((const float4*)WtT)[idx];
    }

    // stage x tail with log_map_zero scaling; wave w owns local nodes [16w,16w+16)
    for (int i = 0; i < 16; ++i) {
        int li = (w << 4) + i;
        int n = __builtin_amdgcn_readfirstlane(base + li);
        float t0 = 0.0f, t1 = 0.0f, x0 = 1.0f;
        if (n < NN) {
            const float* xp = x + (long)n * 129;
            x0 = xp[0];
            t0 = xp[1 + lane];
            t1 = xp[65 + lane];
        }
        // input invariant: x0 = sqrt(1 + sum(tail^2))  ->  ssq = x0^2 - 1
        float dist = arcosh_f(x0);
        float ssq = fmaxf(x0 * x0 - 1.0f, 1e-6f);
        float sc = dist / sqrtf(ssq);
        xt[lane * XT_STRIDE + li]        = sc * t0;
        xt[(64 + lane) * XT_STRIDE + li] = sc * t1;
    }
    __syncthreads();

    const int jg = tid & 31;   // j0 = 4*jg
    const int ng = tid >> 5;   // n0 = 8*ng

    float acc[8][4];
    #pragma unroll
    for (int i = 0; i < 8; ++i)
        #pragma unroll
        for (int jj = 0; jj < 4; ++jj) acc[i][jj] = 0.0f;

    #pragma unroll 4
    for (int k = 0; k < 128; ++k) {
        float4 wv = *(const float4*)&Wt[k * 128 + (jg << 2)];
        float4 xa = *(const float4*)&xt[k * XT_STRIDE + (ng << 3)];
        float4 xb = *(const float4*)&xt[k * XT_STRIDE + (ng << 3) + 4];
        float xv[8] = {xa.x, xa.y, xa.z, xa.w, xb.x, xb.y, xb.z, xb.w};
        float wq[4] = {wv.x, wv.y, wv.z, wv.w};
        #pragma unroll
        for (int i = 0; i < 8; ++i)
            #pragma unroll
            for (int jj = 0; jj < 4; ++jj)
                acc[i][jj] = fmaf(xv[i], wq[jj], acc[i][jj]);
    }

    // epilogue: exp_map_zero, fully in registers (reduce over the 32-lane half)
    float4 bv = *(const float4*)&biasP[jg << 2];
    #pragma unroll
    for (int i = 0; i < 8; ++i) {
        float m0 = acc[i][0] + bv.x;
        float m1 = acc[i][1] + bv.y;
        float m2 = acc[i][2] + bv.z;
        float m3 = acc[i][3] + bv.w;     // c=127 (jg==31): Wt col & bias zero -> 0
        float p = m0 * m0 + m1 * m1 + m2 * m2 + m3 * m3;
        p += __shfl_xor(p, 16, 64);
        p += __shfl_xor(p, 8, 64);
        p += __shfl_xor(p, 4, 64);
        p += __shfl_xor(p, 2, 64);
        p += __shfl_xor(p, 1, 64);       // p = sum_j mx_j^2 (j<127), all 32 lanes
        float n = sqrtf(fmaxf(p, 1e-6f));
        float r = sinhf(fminf(n, 50.0f)) / n;
        int node = base + (ng << 3) + i;
        if (node < NN) {
            float o0 = r * m0, o1 = r * m1, o2 = r * m2, o3 = r * m3;
            if (jg == 31) o3 = sqrtf(1.0f + r * r * p);   // head -> slot 127
            *(float4*)&hh[(long)node * 128 + (jg << 2)] = make_float4(o0, o1, o2, o3);
        }
    }
}

// ---------------------------------------------------------------------------
// Stage 2+3: segment gather-sum, Lorentz centroid normalize, hyp_act.
// hh internal layout (head at slot 127). One wave/node, lane holds c=2l,2l+1.
// ---------------------------------------------------------------------------
__global__ __launch_bounds__(256) void centroid_act_kernel(
        const float* __restrict__ hh, const float* __restrict__ val,
        const int* __restrict__ col, const int* __restrict__ rowptr,
        float* __restrict__ out) {
    const int lane = threadIdx.x & 63;
    const int node = __builtin_amdgcn_readfirstlane(blockIdx.x * 4 + (threadIdx.x >> 6));

    const int lo = rowptr[node], hi = rowptr[node + 1];
    float s0 = 0.0f, s1 = 0.0f;
    int e = lo;
    for (; e + 4 <= hi; e += 4) {
        int c0 = col[e], c1 = col[e + 1], c2 = col[e + 2], c3 = col[e + 3];
        float v0 = val[e], v1 = val[e + 1], v2 = val[e + 2], v3 = val[e + 3];
        float2 a = *(const float2*)&hh[(long)c0 * 128 + 2 * lane];
        float2 b = *(const float2*)&hh[(long)c1 * 128 + 2 * lane];
        float2 c = *(const float2*)&hh[(long)c2 * 128 + 2 * lane];
        float2 d = *(const float2*)&hh[(long)c3 * 128 + 2 * lane];
        s0 = fmaf(v0, a.x, s0); s1 = fmaf(v0, a.y, s1);
        s0 = fmaf(v1, b.x, s0); s1 = fmaf(v1, b.y, s1);
        s0 = fmaf(v2, c.x, s0); s1 = fmaf(v2, c.y, s1);
        s0 = fmaf(v3, d.x, s0); s1 = fmaf(v3, d.y, s1);
    }
    for (; e < hi; ++e) {
        int c = col[e];
        float v = val[e];
        float2 a = *(const float2*)&hh[(long)c * 128 + 2 * lane];
        s0 = fmaf(v, a.x, s0); s1 = fmaf(v, a.y, s1);
    }

    const bool isHead = (lane == 63);   // second slot is c=127 = head
    // Lorentz inner: sum_tail s^2 - s_head^2
    float loc = s0 * s0 + (isHead ? -s1 * s1 : s1 * s1);
    float inner = wred64(loc);
    float coef = 1.0f / sqrtf(fmaxf(fabsf(inner), 1e-6f));
    float g0 = coef * s0, g1 = coef * s1;
    float h20 = coef * __shfl(s1, 63, 64);

    // hyp_act = exp_map_zero(relu(log_map_zero(h2)))
    float dist = arcosh_f(h20);
    float tl = g0 * g0 + (isHead ? 0.0f : g1 * g1);
    float tsq = wred64(tl);
    float scl = dist / sqrtf(fmaxf(tsq, 1e-6f));
    float u0 = fmaxf(scl * g0, 0.0f);
    float u1 = isHead ? 0.0f : fmaxf(scl * g1, 0.0f);
    float S = wred64(u0 * u0 + u1 * u1);
    float n = sqrtf(fmaxf(S, 1e-6f));
    float r = sinhf(fminf(n, 50.0f)) / n;

    float* op = out + (long)node * 128;
    op[1 + 2 * lane] = r * u0;                       // tail c=2l -> out comp 2l+1
    if (lane < 63) op[2 + 2 * lane] = r * u1;        // tail c=2l+1 -> out comp 2l+2
    else           op[0] = sqrtf(1.0f + r * r * S);  // head
}

extern "C" void kernel_launch(void* const* d_in, const int* in_sizes, int n_in,
                              void* d_out, int out_size, void* d_ws, size_t ws_size,
                              hipStream_t stream) {
    const float* x       = (const float*)d_in[0];
    const float* weight  = (const float*)d_in[1];
    const float* bias    = (const float*)d_in[2];
    const float* adj_val = (const float*)d_in[3];
    const int*   adj_row = (const int*)d_in[4];
    const int*   adj_col = (const int*)d_in[5];
    float* out = (float*)d_out;

    char* ws = (char*)d_ws;
    float* hh    = (float*)ws;                              // 25,600,000 B
    int*   rowptr = (int*)(ws + 25600000);                  // 200,004 B
    float* WtT   = (float*)(ws + 25800192);                 // 65,536 B
    float* biasP = (float*)(ws + 25865728);                 // 512 B

    prep_kernel<<<64, 256, 0, stream>>>(weight, bias, WtT, biasP);
    rowptr_kernel<<<(NE + 255) / 256, 256, 0, stream>>>(adj_row, rowptr);
    transform_kernel<<<(NN + 63) / 64, 256, (128 * 128 + 128 * XT_STRIDE) * 4, stream>>>(
        x, WtT, biasP, hh);
    centroid_act_kernel<<<NN / 4, 256, 0, stream>>>(hh, adj_val, adj_col, rowptr, out);
}

// Round 3
// 87.177 us; speedup vs baseline: 2.3286x; 1.6532x over previous
//
#include <hip/hip_runtime.h>
#include <hip/hip_bf16.h>

#define NN 50000
#define NE 800000

typedef __attribute__((ext_vector_type(4))) float f32x4;
typedef __attribute__((ext_vector_type(8))) __bf16 bf16x8;

__device__ __forceinline__ float wred64(float v) {
    v += __shfl_xor(v, 32, 64);
    v += __shfl_xor(v, 16, 64);
    v += __shfl_xor(v, 8, 64);
    v += __shfl_xor(v, 4, 64);
    v += __shfl_xor(v, 2, 64);
    v += __shfl_xor(v, 1, 64);
    return v;
}

__device__ __forceinline__ float arcosh_f(float z) {
    z = fmaxf(z, 1.0f + 1e-7f);
    return logf(z + sqrtf(z * z - 1.0f));
}

// ---------------------------------------------------------------------------
// prep: pack W^T into MFMA B-fragment-linear order as bf16 hi/lo pair.
// frag f = jt*4 + t; lane l; elem i:  true_k = 32*(l>>4) + 8*t + i,
// col = 16*jt + (l&15).  B[k][col] = weight[col*128 + k] (col 127 zeroed).
// The same k-permutation is used for the A-fragments -> sum over k invariant.
// ---------------------------------------------------------------------------
__global__ void prep_kernel(const float* __restrict__ weight, const float* __restrict__ bias,
                            ushort* __restrict__ WfHi, ushort* __restrict__ WfLo,
                            float* __restrict__ biasP) {
    int t8 = blockIdx.x * 256 + threadIdx.x;   // 0..2047 over grid of 8 blocks
    int l = t8 & 63, f = t8 >> 6;
    int t = f & 3, jt = f >> 2;
    int g = l >> 4, r = l & 15;
    int col = jt * 16 + r;
    #pragma unroll
    for (int i = 0; i < 8; ++i) {
        int k = 32 * g + 8 * t + i;
        float v = (col < 127) ? weight[col * 128 + k] : 0.0f;
        __bf16 h = (__bf16)v;
        float lo = v - (float)h;
        __bf16 lb = (__bf16)lo;
        WfHi[t8 * 8 + i] = __builtin_bit_cast(unsigned short, h);
        WfLo[t8 * 8 + i] = __builtin_bit_cast(unsigned short, lb);
    }
    if (t8 < 128) biasP[t8] = (t8 < 127) ? bias[t8] : 0.0f;
}

// ---------------------------------------------------------------------------
// rowptr[r] = first edge with row >= r (rows sorted)
// ---------------------------------------------------------------------------
__global__ void rowptr_kernel(const int* __restrict__ row, int* __restrict__ rowptr) {
    int e = blockIdx.x * 256 + threadIdx.x;
    if (e >= NE) return;
    int r1 = row[e];
    int r0 = (e == 0) ? -1 : row[e - 1];
    for (int r = r0 + 1; r <= r1; ++r) rowptr[r] = e;
    if (e == NE - 1) {
        for (int r = r1 + 1; r <= NN; ++r) rowptr[r] = NE;
    }
}

// ---------------------------------------------------------------------------
// Stage 1 via MFMA (bf16x3 compensated): hh = exp_map_zero([0, W@log0(x)+b])
// Block: 256 threads / 4 waves, 64 nodes (16 per wave). K=128, N=128.
// Internal layout: hh[node][c] = tail_{c} for c<127, hh[node][127] = head.
// ---------------------------------------------------------------------------
__global__ __launch_bounds__(256) void transform_kernel(
        const float* __restrict__ x, const ushort* __restrict__ Wf /* hi|lo 64KB */,
        const float* __restrict__ biasP, float* __restrict__ hh) {
    __shared__ __align__(16) ushort WF[32768];   // 64 KB: [0,16384) hi, rest lo

    const int tid = threadIdx.x;
    #pragma unroll
    for (int i = 0; i < 16; ++i)
        ((float4*)WF)[i * 256 + tid] = ((const float4*)Wf)[i * 256 + tid];

    const int lane = tid & 63, w = tid >> 6;
    const int g = lane >> 4, r = lane & 15;
    const int nodeA = blockIdx.x * 64 + w * 16 + r;   // A-fragment row

    // A: xt[row][k'] for k' = 32g..32g+31 (one contiguous 128B span per lane)
    float xv[32];
    float x0 = 1.0f;
    if (nodeA < NN) {
        const float* xp = x + (long)nodeA * 129;
        x0 = xp[0];
        __builtin_memcpy(xv, xp + 1 + 32 * g, 128);
    } else {
        #pragma unroll
        for (int i = 0; i < 32; ++i) xv[i] = 0.0f;
    }
    // input invariant: x0 = sqrt(1 + sum tail^2)  ->  ssq = x0^2 - 1
    float dist = arcosh_f(x0);
    float sc = dist / sqrtf(fmaxf(x0 * x0 - 1.0f, 1e-6f));

    bf16x8 ah[4], al[4];
    #pragma unroll
    for (int t = 0; t < 4; ++t) {
        #pragma unroll
        for (int i = 0; i < 8; ++i) {
            float v = sc * xv[8 * t + i];
            __bf16 h = (__bf16)v;
            ah[t][i] = h;
            al[t][i] = (__bf16)(v - (float)h);
        }
    }
    __syncthreads();

    f32x4 acc[8];
    #pragma unroll
    for (int jt = 0; jt < 8; ++jt) acc[jt] = (f32x4){0.0f, 0.0f, 0.0f, 0.0f};

    #pragma unroll
    for (int jt = 0; jt < 8; ++jt) {
        #pragma unroll
        for (int t = 0; t < 4; ++t) {
            const int f = jt * 4 + t;
            bf16x8 bh = *(const bf16x8*)&WF[(f * 64 + lane) * 8];
            bf16x8 bl = *(const bf16x8*)&WF[16384 + (f * 64 + lane) * 8];
            acc[jt] = __builtin_amdgcn_mfma_f32_16x16x32_bf16(al[t], bh, acc[jt], 0, 0, 0);
            acc[jt] = __builtin_amdgcn_mfma_f32_16x16x32_bf16(ah[t], bl, acc[jt], 0, 0, 0);
            acc[jt] = __builtin_amdgcn_mfma_f32_16x16x32_bf16(ah[t], bh, acc[jt], 0, 0, 0);
        }
    }

    float bv[8];
    #pragma unroll
    for (int jt = 0; jt < 8; ++jt) bv[jt] = biasP[jt * 16 + r];

    // C/D: lane holds rows 4g+i (i=0..3), col = 16jt + r
    #pragma unroll
    for (int i = 0; i < 4; ++i) {
        float m[8];
        float p = 0.0f;
        #pragma unroll
        for (int jt = 0; jt < 8; ++jt) {
            m[jt] = acc[jt][i] + bv[jt];
            p = fmaf(m[jt], m[jt], p);
        }
        p += __shfl_xor(p, 1, 64);
        p += __shfl_xor(p, 2, 64);
        p += __shfl_xor(p, 4, 64);
        p += __shfl_xor(p, 8, 64);        // p = sum_{j<127} mx_j^2 (col 127 is 0)
        float n = sqrtf(fmaxf(p, 1e-6f));
        float rr = sinhf(fminf(n, 50.0f)) / n;
        int node = blockIdx.x * 64 + w * 16 + g * 4 + i;
        if (node < NN) {
            float* hp = hh + (long)node * 128;
            #pragma unroll
            for (int jt = 0; jt < 8; ++jt) {
                int j = jt * 16 + r;
                hp[j] = (j == 127) ? sqrtf(1.0f + rr * rr * p) : rr * m[jt];
            }
        }
    }
}

// ---------------------------------------------------------------------------
// Stage 2+3: segment gather-sum, Lorentz centroid normalize, hyp_act.
// hh internal layout (head at slot 127). One wave/node, lane holds c=2l,2l+1.
// ---------------------------------------------------------------------------
__global__ __launch_bounds__(256) void centroid_act_kernel(
        const float* __restrict__ hh, const float* __restrict__ val,
        const int* __restrict__ col, const int* __restrict__ rowptr,
        float* __restrict__ out) {
    const int lane = threadIdx.x & 63;
    const int node = __builtin_amdgcn_readfirstlane(blockIdx.x * 4 + (threadIdx.x >> 6));

    const int lo = rowptr[node], hi = rowptr[node + 1];
    float s0 = 0.0f, s1 = 0.0f;
    int e = lo;
    for (; e + 4 <= hi; e += 4) {
        int c0 = col[e], c1 = col[e + 1], c2 = col[e + 2], c3 = col[e + 3];
        float v0 = val[e], v1 = val[e + 1], v2 = val[e + 2], v3 = val[e + 3];
        float2 a = *(const float2*)&hh[(long)c0 * 128 + 2 * lane];
        float2 b = *(const float2*)&hh[(long)c1 * 128 + 2 * lane];
        float2 c = *(const float2*)&hh[(long)c2 * 128 + 2 * lane];
        float2 d = *(const float2*)&hh[(long)c3 * 128 + 2 * lane];
        s0 = fmaf(v0, a.x, s0); s1 = fmaf(v0, a.y, s1);
        s0 = fmaf(v1, b.x, s0); s1 = fmaf(v1, b.y, s1);
        s0 = fmaf(v2, c.x, s0); s1 = fmaf(v2, c.y, s1);
        s0 = fmaf(v3, d.x, s0); s1 = fmaf(v3, d.y, s1);
    }
    for (; e < hi; ++e) {
        int c = col[e];
        float v = val[e];
        float2 a = *(const float2*)&hh[(long)c * 128 + 2 * lane];
        s0 = fmaf(v, a.x, s0); s1 = fmaf(v, a.y, s1);
    }

    const bool isHead = (lane == 63);   // lane 63's second slot is c=127 = head
    float loc = s0 * s0 + (isHead ? -s1 * s1 : s1 * s1);
    float inner = wred64(loc);
    float coef = 1.0f / sqrtf(fmaxf(fabsf(inner), 1e-6f));
    float g0 = coef * s0, g1 = coef * s1;
    float h20 = coef * __shfl(s1, 63, 64);

    float dist = arcosh_f(h20);
    float tl = g0 * g0 + (isHead ? 0.0f : g1 * g1);
    float tsq = wred64(tl);
    float scl = dist / sqrtf(fmaxf(tsq, 1e-6f));
    float u0 = fmaxf(scl * g0, 0.0f);
    float u1 = isHead ? 0.0f : fmaxf(scl * g1, 0.0f);
    float S = wred64(u0 * u0 + u1 * u1);
    float n = sqrtf(fmaxf(S, 1e-6f));
    float r = sinhf(fminf(n, 50.0f)) / n;

    float* op = out + (long)node * 128;
    op[1 + 2 * lane] = r * u0;                       // tail c=2l -> out comp 2l+1
    if (lane < 63) op[2 + 2 * lane] = r * u1;        // tail c=2l+1 -> out comp 2l+2
    else           op[0] = sqrtf(1.0f + r * r * S);  // head
}

extern "C" void kernel_launch(void* const* d_in, const int* in_sizes, int n_in,
                              void* d_out, int out_size, void* d_ws, size_t ws_size,
                              hipStream_t stream) {
    const float* x       = (const float*)d_in[0];
    const float* weight  = (const float*)d_in[1];
    const float* bias    = (const float*)d_in[2];
    const float* adj_val = (const float*)d_in[3];
    const int*   adj_row = (const int*)d_in[4];
    const int*   adj_col = (const int*)d_in[5];
    float* out = (float*)d_out;

    char* ws = (char*)d_ws;
    float*  hh     = (float*)ws;                      // 25,600,000 B
    int*    rowptr = (int*)(ws + 25600000);           // 200,004 B
    ushort* WfHi   = (ushort*)(ws + 25800192);        // 32,768 B
    ushort* WfLo   = (ushort*)(ws + 25832960);        // 32,768 B (contiguous w/ hi)
    float*  biasP  = (float*)(ws + 25865728);         // 512 B

    prep_kernel<<<8, 256, 0, stream>>>(weight, bias, WfHi, WfLo, biasP);
    rowptr_kernel<<<(NE + 255) / 256, 256, 0, stream>>>(adj_row, rowptr);
    transform_kernel<<<(NN + 63) / 64, 256, 0, stream>>>(x, WfHi, biasP, hh);
    centroid_act_kernel<<<NN / 4, 256, 0, stream>>>(hh, adj_val, adj_col, rowptr, out);
}